// Round 1
// baseline (435.130 us; speedup 1.0000x reference)
//
#include <hip/hip_runtime.h>
#include <hip/hip_bf16.h>

// ---------------- CSR build ----------------

__global__ __launch_bounds__(256) void count_k(const int* __restrict__ col, int* __restrict__ cnt, int E) {
    int e = blockIdx.x * 256 + threadIdx.x;
    if (e < E) atomicAdd(&cnt[col[e]], 1);
}

__global__ __launch_bounds__(256) void dis_k(const int* __restrict__ cnt, float* __restrict__ dis, int n) {
    int i = blockIdx.x * 256 + threadIdx.x;
    if (i < n) dis[i] = rsqrtf(1.0f + (float)cnt[i]);
}

__global__ __launch_bounds__(256) void scan_a(const int* __restrict__ cnt, int* __restrict__ tmp,
                                              int* __restrict__ bsum, int n) {
    __shared__ int s[256];
    int t = threadIdx.x;
    int i = blockIdx.x * 256 + t;
    int v = (i < n) ? cnt[i] : 0;
    s[t] = v;
    __syncthreads();
    #pragma unroll
    for (int off = 1; off < 256; off <<= 1) {
        int add = (t >= off) ? s[t - off] : 0;
        __syncthreads();
        s[t] += add;
        __syncthreads();
    }
    if (i < n) tmp[i] = s[t];           // inclusive within block
    if (t == 255) bsum[blockIdx.x] = s[255];
}

__global__ __launch_bounds__(256) void scan_b(int* __restrict__ bsum, int nb) {
    __shared__ int s[256];
    int t = threadIdx.x;
    int v = (t < nb) ? bsum[t] : 0;
    s[t] = v;
    __syncthreads();
    #pragma unroll
    for (int off = 1; off < 256; off <<= 1) {
        int add = (t >= off) ? s[t - off] : 0;
        __syncthreads();
        s[t] += add;
        __syncthreads();
    }
    if (t < nb) bsum[t] = s[t] - v;     // exclusive block offsets
}

__global__ __launch_bounds__(256) void scan_c(const int* __restrict__ cnt, const int* __restrict__ tmp,
                                              const int* __restrict__ bsum, int* __restrict__ rowptr,
                                              int n, int E) {
    int i = blockIdx.x * 256 + threadIdx.x;
    if (i < n) rowptr[i] = bsum[blockIdx.x] + tmp[i] - cnt[i];   // global exclusive
    if (i == 0) rowptr[n] = E;
}

__global__ __launch_bounds__(256) void fill_k(const int* __restrict__ row, const int* __restrict__ col,
                                              const int* __restrict__ rowptr, int* __restrict__ cnt2,
                                              const float* __restrict__ dis,
                                              int* __restrict__ csr_src, float* __restrict__ csr_w, int E) {
    int e = blockIdx.x * 256 + threadIdx.x;
    if (e >= E) return;
    int r = row[e], t = col[e];
    int p = atomicAdd(&cnt2[t], 1);
    int slot = rowptr[t] + p;
    csr_src[slot] = r;
    csr_w[slot] = dis[r] * dis[t];
}

// ---------------- dense GEMM: O[n][128] = A[n][128] @ W[128][128] ----------------

__global__ __launch_bounds__(256) void gemm128(const float* __restrict__ A, const float* __restrict__ W,
                                               float* __restrict__ O, int nrows) {
    __shared__ float sA[32][68];    // [k][r], padded: 68%4==0 (16B align), 68%32==4 (bank spread)
    __shared__ float sW[32][128];   // [k][c]
    int tid = threadIdx.x;
    int row0 = blockIdx.x * 64;
    int cg = tid & 31;              // col group -> 4 cols
    int rg = tid >> 5;              // row group -> 8 rows
    int c0 = cg * 4;
    int r0 = rg * 8;
    float acc[8][4] = {};
    for (int kc = 0; kc < 4; ++kc) {
        #pragma unroll
        for (int i = 0; i < 8; ++i) {            // A chunk 64x32, transposed into LDS
            int idx = tid + i * 256;
            int r = idx >> 5, k = idx & 31;
            int grow = row0 + r;
            sA[k][r] = (grow < nrows) ? A[grow * 128 + kc * 32 + k] : 0.0f;
        }
        #pragma unroll
        for (int i = 0; i < 16; ++i) {           // W chunk 32x128
            int idx = tid + i * 256;
            int k = idx >> 7, c = idx & 127;
            sW[k][c] = W[(kc * 32 + k) * 128 + c];
        }
        __syncthreads();
        #pragma unroll
        for (int k = 0; k < 32; ++k) {
            float4 w4 = *reinterpret_cast<const float4*>(&sW[k][c0]);
            float4 a0 = *reinterpret_cast<const float4*>(&sA[k][r0]);
            float4 a1 = *reinterpret_cast<const float4*>(&sA[k][r0 + 4]);
            float ar[8] = {a0.x, a0.y, a0.z, a0.w, a1.x, a1.y, a1.z, a1.w};
            float wr[4] = {w4.x, w4.y, w4.z, w4.w};
            #pragma unroll
            for (int i = 0; i < 8; ++i)
                #pragma unroll
                for (int j = 0; j < 4; ++j)
                    acc[i][j] += ar[i] * wr[j];
        }
        __syncthreads();
    }
    #pragma unroll
    for (int i = 0; i < 8; ++i) {
        int grow = row0 + r0 + i;
        if (grow < nrows) {
            float4 v = {acc[i][0], acc[i][1], acc[i][2], acc[i][3]};
            *reinterpret_cast<float4*>(&O[grow * 128 + c0]) = v;
        }
    }
}

// ---------------- aggregation: out[n] = relu( sum_{e->n} w_e * h[src_e] + dis[n]^2 * h[n] + b ) ----------------

__global__ __launch_bounds__(256) void agg_k(const float* __restrict__ h, const int* __restrict__ rowptr,
                                             const int* __restrict__ src, const float* __restrict__ w,
                                             const float* __restrict__ dis, const float* __restrict__ bias,
                                             float* __restrict__ out, int n) {
    int node = blockIdx.x * 2 + (threadIdx.x >> 7);
    int c = threadIdx.x & 127;
    if (node >= n) return;
    float d = dis[node];
    float acc = h[node * 128 + c] * d * d;
    float acc2 = 0.0f;
    int s = rowptr[node], e = rowptr[node + 1];
    int i = s;
    for (; i + 1 < e; i += 2) {
        int s0 = src[i], s1 = src[i + 1];
        float w0 = w[i], w1 = w[i + 1];
        acc  += h[s0 * 128 + c] * w0;
        acc2 += h[s1 * 128 + c] * w1;
    }
    if (i < e) acc += h[src[i] * 128 + c] * w[i];
    float v = acc + acc2 + bias[c];
    out[node * 128 + c] = v > 0.0f ? v : 0.0f;
}

// ---------------- pooling ----------------

__global__ __launch_bounds__(256) void bounds_k(const int* __restrict__ batch, int* __restrict__ start,
                                                int n, int g) {
    int i = blockIdx.x * 256 + threadIdx.x;
    if (i >= n) return;
    int b = batch[i];
    int bp = (i == 0) ? -1 : batch[i - 1];
    for (int q = bp + 1; q <= b; ++q) start[q] = i;
    if (i == n - 1) for (int q = b + 1; q <= g; ++q) start[q] = n;
}

__global__ __launch_bounds__(128) void pool_k(const float* __restrict__ a, const int* __restrict__ start,
                                              float* __restrict__ sums) {
    int g = blockIdx.x >> 2;
    int chunk = blockIdx.x & 3;
    int c = threadIdx.x;  // 128
    int s = start[g], e = start[g + 1];
    int len = e - s;
    int per = (len + 3) >> 2;
    int cs = s + chunk * per;
    int ce = min(cs + per, e);
    float acc = 0.0f;
    for (int nidx = cs; nidx < ce; ++nidx) acc += a[nidx * 128 + c];
    if (ce > cs) atomicAdd(&sums[g * 128 + c], acc);
}

__global__ __launch_bounds__(128) void final_k(const float* __restrict__ sums, const int* __restrict__ start,
                                               const float* __restrict__ Wc, const float* __restrict__ bc,
                                               float* __restrict__ outp, int C) {
    __shared__ float sp[128];
    int g = blockIdx.x;
    int t = threadIdx.x;  // 128
    float cntf = fmaxf((float)(start[g + 1] - start[g]), 1.0f);
    sp[t] = sums[g * 128 + t] / cntf;
    __syncthreads();
    if (t < C) {
        float acc = bc[t];
        #pragma unroll 8
        for (int cc = 0; cc < 128; ++cc) acc += sp[cc] * Wc[cc * C + t];
        outp[g * C + t] = acc;
    }
}

// ---------------- launcher ----------------

extern "C" void kernel_launch(void* const* d_in, const int* in_sizes, int n_in,
                              void* d_out, int out_size, void* d_ws, size_t ws_size,
                              hipStream_t stream) {
    const float* x    = (const float*)d_in[0];
    const int*   ei   = (const int*)d_in[1];
    const int*   batch= (const int*)d_in[2];
    const float* W1   = (const float*)d_in[3];
    const float* b1   = (const float*)d_in[4];
    const float* W2   = (const float*)d_in[5];
    const float* b2   = (const float*)d_in[6];
    const float* Wc   = (const float*)d_in[7];
    const float* bc   = (const float*)d_in[8];

    const int N = in_sizes[0] / 128;
    const int E = in_sizes[1] / 2;
    const int C = in_sizes[7] / 128;
    const int G = out_size / C;

    const int* row = ei;         // edge_index[0]
    const int* col = ei + E;     // edge_index[1]

    char* ws = (char*)d_ws;
    size_t o = 0;
    auto take = [&](size_t nbytes) -> char* {
        char* p = ws + o;
        o = (o + nbytes + 255) & ~(size_t)255;
        return p;
    };
    int*   cnt     = (int*)take((size_t)N * 4);
    int*   cnt2    = (int*)take((size_t)N * 4);
    float* sums    = (float*)take((size_t)G * 128 * 4);
    size_t zero_span = o;                       // cnt, cnt2, sums zeroed together
    int*   rowptr  = (int*)take((size_t)(N + 1) * 4);
    int*   tmp     = (int*)take((size_t)N * 4);
    int*   bsum    = (int*)take(256 * 4);
    float* dis     = (float*)take((size_t)N * 4);
    int*   start   = (int*)take((size_t)(G + 1) * 4);
    int*   csr_src = (int*)take((size_t)E * 4);
    float* csr_w   = (float*)take((size_t)E * 4);
    float* bufA    = (float*)take((size_t)N * 128 * 4);
    float* bufB    = (float*)take((size_t)N * 128 * 4);

    hipMemsetAsync(d_ws, 0, zero_span, stream);

    int gE = (E + 255) / 256;
    int gN = (N + 255) / 256;

    count_k<<<gE, 256, 0, stream>>>(col, cnt, E);
    dis_k<<<gN, 256, 0, stream>>>(cnt, dis, N);
    scan_a<<<gN, 256, 0, stream>>>(cnt, tmp, bsum, N);
    scan_b<<<1, 256, 0, stream>>>(bsum, gN);
    scan_c<<<gN, 256, 0, stream>>>(cnt, tmp, bsum, rowptr, N, E);
    fill_k<<<gE, 256, 0, stream>>>(row, col, rowptr, cnt2, dis, csr_src, csr_w, E);

    int gGemm = (N + 63) / 64;
    int gAgg  = (N + 1) / 2;

    gemm128<<<gGemm, 256, 0, stream>>>(x, W1, bufA, N);
    agg_k<<<gAgg, 256, 0, stream>>>(bufA, rowptr, csr_src, csr_w, dis, b1, bufB, N);
    gemm128<<<gGemm, 256, 0, stream>>>(bufB, W2, bufA, N);
    agg_k<<<gAgg, 256, 0, stream>>>(bufA, rowptr, csr_src, csr_w, dis, b2, bufB, N);

    bounds_k<<<gN, 256, 0, stream>>>(batch, start, N, G);
    pool_k<<<G * 4, 128, 0, stream>>>(bufB, start, sums);
    final_k<<<G, 128, 0, stream>>>(sums, start, Wc, bc, (float*)d_out, C);
}

// Round 2
// 355.198 us; speedup vs baseline: 1.2250x; 1.2250x over previous
//
#include <hip/hip_runtime.h>
#include <hip/hip_bf16.h>

// ---------------- CSR build ----------------

__global__ __launch_bounds__(256) void count_k(const int* __restrict__ col, int* __restrict__ cnt, int E) {
    int e = blockIdx.x * 256 + threadIdx.x;
    if (e < E) atomicAdd(&cnt[col[e]], 1);
}

__global__ __launch_bounds__(256) void dis_k(const int* __restrict__ cnt, float* __restrict__ dis, int n) {
    int i = blockIdx.x * 256 + threadIdx.x;
    if (i < n) dis[i] = rsqrtf(1.0f + (float)cnt[i]);
}

__global__ __launch_bounds__(256) void scan_a(const int* __restrict__ cnt, int* __restrict__ tmp,
                                              int* __restrict__ bsum, int n) {
    __shared__ int s[256];
    int t = threadIdx.x;
    int i = blockIdx.x * 256 + t;
    int v = (i < n) ? cnt[i] : 0;
    s[t] = v;
    __syncthreads();
    #pragma unroll
    for (int off = 1; off < 256; off <<= 1) {
        int add = (t >= off) ? s[t - off] : 0;
        __syncthreads();
        s[t] += add;
        __syncthreads();
    }
    if (i < n) tmp[i] = s[t];           // inclusive within block
    if (t == 255) bsum[blockIdx.x] = s[255];
}

__global__ __launch_bounds__(256) void scan_b(int* __restrict__ bsum, int nb) {
    __shared__ int s[256];
    int t = threadIdx.x;
    int v = (t < nb) ? bsum[t] : 0;
    s[t] = v;
    __syncthreads();
    #pragma unroll
    for (int off = 1; off < 256; off <<= 1) {
        int add = (t >= off) ? s[t - off] : 0;
        __syncthreads();
        s[t] += add;
        __syncthreads();
    }
    if (t < nb) bsum[t] = s[t] - v;     // exclusive block offsets
}

__global__ __launch_bounds__(256) void scan_c(const int* __restrict__ cnt, const int* __restrict__ tmp,
                                              const int* __restrict__ bsum, int* __restrict__ rowptr,
                                              int n, int E) {
    int i = blockIdx.x * 256 + threadIdx.x;
    if (i < n) rowptr[i] = bsum[blockIdx.x] + tmp[i] - cnt[i];   // global exclusive
    if (i == 0) rowptr[n] = E;
}

__global__ __launch_bounds__(256) void fill_k(const int* __restrict__ row, const int* __restrict__ col,
                                              const int* __restrict__ rowptr, int* __restrict__ cnt2,
                                              const float* __restrict__ dis,
                                              int2* __restrict__ csr_sw, int E) {
    int e = blockIdx.x * 256 + threadIdx.x;
    if (e >= E) return;
    int r = row[e], t = col[e];
    int p = atomicAdd(&cnt2[t], 1);
    int slot = rowptr[t] + p;
    int2 pack;
    pack.x = r;
    pack.y = __float_as_int(dis[r] * dis[t]);
    csr_sw[slot] = pack;
}

// ---------------- dense GEMM: O[n][128] = A[n][128] @ W[128][128] ----------------

__global__ __launch_bounds__(256) void gemm128(const float* __restrict__ A, const float* __restrict__ W,
                                               float* __restrict__ O, int nrows) {
    __shared__ float sA[32][68];    // [k][r], padded
    __shared__ float sW[32][128];   // [k][c]
    int tid = threadIdx.x;
    int row0 = blockIdx.x * 64;
    int cg = tid & 31;              // col group -> 4 cols
    int rg = tid >> 5;              // row group -> 8 rows
    int c0 = cg * 4;
    int r0 = rg * 8;
    float acc[8][4] = {};
    for (int kc = 0; kc < 4; ++kc) {
        #pragma unroll
        for (int i = 0; i < 8; ++i) {            // A chunk 64x32, transposed into LDS
            int idx = tid + i * 256;
            int r = idx >> 5, k = idx & 31;
            int grow = row0 + r;
            sA[k][r] = (grow < nrows) ? A[grow * 128 + kc * 32 + k] : 0.0f;
        }
        #pragma unroll
        for (int i = 0; i < 16; ++i) {           // W chunk 32x128
            int idx = tid + i * 256;
            int k = idx >> 7, c = idx & 127;
            sW[k][c] = W[(kc * 32 + k) * 128 + c];
        }
        __syncthreads();
        #pragma unroll
        for (int k = 0; k < 32; ++k) {
            float4 w4 = *reinterpret_cast<const float4*>(&sW[k][c0]);
            float4 a0 = *reinterpret_cast<const float4*>(&sA[k][r0]);
            float4 a1 = *reinterpret_cast<const float4*>(&sA[k][r0 + 4]);
            float ar[8] = {a0.x, a0.y, a0.z, a0.w, a1.x, a1.y, a1.z, a1.w};
            float wr[4] = {w4.x, w4.y, w4.z, w4.w};
            #pragma unroll
            for (int i = 0; i < 8; ++i)
                #pragma unroll
                for (int j = 0; j < 4; ++j)
                    acc[i][j] += ar[i] * wr[j];
        }
        __syncthreads();
    }
    #pragma unroll
    for (int i = 0; i < 8; ++i) {
        int grow = row0 + r0 + i;
        if (grow < nrows) {
            float4 v = {acc[i][0], acc[i][1], acc[i][2], acc[i][3]};
            *reinterpret_cast<float4*>(&O[grow * 128 + c0]) = v;
        }
    }
}

// ---------------- aggregation: out[n] = relu( sum_{e->n} w_e * h[src_e] + dis[n]^2 * h[n] + b ) ----------------
// one wave (64 lanes) per node; each lane owns 2 channels (float2); 4-deep unrolled gathers

__global__ __launch_bounds__(256) void agg_k(const float* __restrict__ h, const int* __restrict__ rowptr,
                                             const int2* __restrict__ csr, const float* __restrict__ dis,
                                             const float* __restrict__ bias,
                                             float* __restrict__ out, int n) {
    int wave = threadIdx.x >> 6;
    int lane = threadIdx.x & 63;
    int node = blockIdx.x * 4 + wave;
    if (node >= n) return;
    const float2* h2 = (const float2*)h;
    float d = dis[node];
    float2 self = h2[node * 64 + lane];
    float2 acc0, acc1 = {0.f, 0.f}, acc2 = {0.f, 0.f}, acc3 = {0.f, 0.f};
    acc0.x = self.x * d * d;
    acc0.y = self.y * d * d;
    int s = rowptr[node], e = rowptr[node + 1];
    int i = s;
    for (; i + 3 < e; i += 4) {
        int2 p0 = csr[i], p1 = csr[i + 1], p2 = csr[i + 2], p3 = csr[i + 3];
        float2 v0 = h2[p0.x * 64 + lane];
        float2 v1 = h2[p1.x * 64 + lane];
        float2 v2 = h2[p2.x * 64 + lane];
        float2 v3 = h2[p3.x * 64 + lane];
        float w0 = __int_as_float(p0.y), w1 = __int_as_float(p1.y);
        float w2 = __int_as_float(p2.y), w3 = __int_as_float(p3.y);
        acc0.x += v0.x * w0; acc0.y += v0.y * w0;
        acc1.x += v1.x * w1; acc1.y += v1.y * w1;
        acc2.x += v2.x * w2; acc2.y += v2.y * w2;
        acc3.x += v3.x * w3; acc3.y += v3.y * w3;
    }
    for (; i < e; ++i) {
        int2 p0 = csr[i];
        float2 v0 = h2[p0.x * 64 + lane];
        float w0 = __int_as_float(p0.y);
        acc0.x += v0.x * w0; acc0.y += v0.y * w0;
    }
    const float2* b2 = (const float2*)bias;
    float2 bb = b2[lane];
    float vx = acc0.x + acc1.x + acc2.x + acc3.x + bb.x;
    float vy = acc0.y + acc1.y + acc2.y + acc3.y + bb.y;
    float2 res;
    res.x = vx > 0.f ? vx : 0.f;
    res.y = vy > 0.f ? vy : 0.f;
    ((float2*)out)[node * 64 + lane] = res;
}

// ---------------- pooling ----------------

__global__ __launch_bounds__(256) void bounds_k(const int* __restrict__ batch, int* __restrict__ start,
                                                int n, int g) {
    int i = blockIdx.x * 256 + threadIdx.x;
    if (i >= n) return;
    int b = batch[i];
    int bp = (i == 0) ? -1 : batch[i - 1];
    for (int q = bp + 1; q <= b; ++q) start[q] = i;
    if (i == n - 1) for (int q = b + 1; q <= g; ++q) start[q] = n;
}

__global__ __launch_bounds__(128) void pool_k(const float* __restrict__ a, const int* __restrict__ start,
                                              float* __restrict__ sums) {
    int g = blockIdx.x >> 2;
    int chunk = blockIdx.x & 3;
    int c = threadIdx.x;  // 128
    int s = start[g], e = start[g + 1];
    int len = e - s;
    int per = (len + 3) >> 2;
    int cs = s + chunk * per;
    int ce = min(cs + per, e);
    float acc = 0.0f;
    for (int nidx = cs; nidx < ce; ++nidx) acc += a[nidx * 128 + c];
    if (ce > cs) atomicAdd(&sums[g * 128 + c], acc);
}

__global__ __launch_bounds__(128) void final_k(const float* __restrict__ sums, const int* __restrict__ start,
                                               const float* __restrict__ Wc, const float* __restrict__ bc,
                                               float* __restrict__ outp, int C) {
    __shared__ float sp[128];
    int g = blockIdx.x;
    int t = threadIdx.x;  // 128
    float cntf = fmaxf((float)(start[g + 1] - start[g]), 1.0f);
    sp[t] = sums[g * 128 + t] / cntf;
    __syncthreads();
    if (t < C) {
        float acc = bc[t];
        #pragma unroll 8
        for (int cc = 0; cc < 128; ++cc) acc += sp[cc] * Wc[cc * C + t];
        outp[g * C + t] = acc;
    }
}

// ---------------- launcher ----------------

extern "C" void kernel_launch(void* const* d_in, const int* in_sizes, int n_in,
                              void* d_out, int out_size, void* d_ws, size_t ws_size,
                              hipStream_t stream) {
    const float* x    = (const float*)d_in[0];
    const int*   ei   = (const int*)d_in[1];
    const int*   batch= (const int*)d_in[2];
    const float* W1   = (const float*)d_in[3];
    const float* b1   = (const float*)d_in[4];
    const float* W2   = (const float*)d_in[5];
    const float* b2   = (const float*)d_in[6];
    const float* Wc   = (const float*)d_in[7];
    const float* bc   = (const float*)d_in[8];

    const int N = in_sizes[0] / 128;
    const int E = in_sizes[1] / 2;
    const int C = in_sizes[7] / 128;
    const int G = out_size / C;

    const int* row = ei;         // edge_index[0]
    const int* col = ei + E;     // edge_index[1]

    char* ws = (char*)d_ws;
    size_t o = 0;
    auto take = [&](size_t nbytes) -> char* {
        char* p = ws + o;
        o = (o + nbytes + 255) & ~(size_t)255;
        return p;
    };
    int*   cnt     = (int*)take((size_t)N * 4);
    int*   cnt2    = (int*)take((size_t)N * 4);
    float* sums    = (float*)take((size_t)G * 128 * 4);
    size_t zero_span = o;                       // cnt, cnt2, sums zeroed together
    int*   rowptr  = (int*)take((size_t)(N + 1) * 4);
    int*   tmp     = (int*)take((size_t)N * 4);
    int*   bsum    = (int*)take(256 * 4);
    float* dis     = (float*)take((size_t)N * 4);
    int*   start   = (int*)take((size_t)(G + 1) * 4);
    int2*  csr_sw  = (int2*)take((size_t)E * 8);
    float* bufA    = (float*)take((size_t)N * 128 * 4);
    float* bufB    = (float*)take((size_t)N * 128 * 4);

    hipMemsetAsync(d_ws, 0, zero_span, stream);

    int gE = (E + 255) / 256;
    int gN = (N + 255) / 256;

    count_k<<<gE, 256, 0, stream>>>(col, cnt, E);
    dis_k<<<gN, 256, 0, stream>>>(cnt, dis, N);
    scan_a<<<gN, 256, 0, stream>>>(cnt, tmp, bsum, N);
    scan_b<<<1, 256, 0, stream>>>(bsum, gN);
    scan_c<<<gN, 256, 0, stream>>>(cnt, tmp, bsum, rowptr, N, E);
    fill_k<<<gE, 256, 0, stream>>>(row, col, rowptr, cnt2, dis, csr_sw, E);

    int gGemm = (N + 63) / 64;
    int gAgg  = (N + 3) / 4;

    gemm128<<<gGemm, 256, 0, stream>>>(x, W1, bufA, N);
    agg_k<<<gAgg, 256, 0, stream>>>(bufA, rowptr, csr_sw, dis, b1, bufB, N);
    gemm128<<<gGemm, 256, 0, stream>>>(bufB, W2, bufA, N);
    agg_k<<<gAgg, 256, 0, stream>>>(bufA, rowptr, csr_sw, dis, b2, bufB, N);

    bounds_k<<<gN, 256, 0, stream>>>(batch, start, N, G);
    pool_k<<<G * 4, 128, 0, stream>>>(bufB, start, sums);
    final_k<<<G, 128, 0, stream>>>(sums, start, Wc, bc, (float*)d_out, C);
}